// Round 5
// baseline (525.266 us; speedup 1.0000x reference)
//
#include <hip/hip_runtime.h>
#include <hip/hip_bf16.h>

// Problem: B=16, C=256, H=64, L=40, TD=768, NC=8, EMB=392
// R7: dispatch-count collapse 8 -> 3 (measured ~15-20us per-dispatch overhead).
// R8: mega1 restructure (langmlp first, wave-per-plane wsum). mega1 115 -> off top-5.
// R9: FAILED (456us): launch_bounds(512,4) reg cap -> scratch spills.
// R10: R8 structure + bijective XCD swizzle. FETCH 108->85MB, dur 112->109.
// R11: FAILED (423us): full kk-unroll blew the (256,2) ~256-reg cap -> spills
//   (WRITE_SIZE 65->127MB). Lesson: keep live set under 256 unified regs.
// R12: c3f conv LDS-traffic cut. Analysis: conv critical path is the LDS read stream
//   (144 ds_read_b128/wave/cc = 1.15MB/CU/cc ~ 13.9K cyc vs MFMA 5.5K cyc). Rows
//   r=half+ky alias across (half,ky) pairs: load 4 rows ONCE per (kx,k32) and pair
//   A[ky]/A[ky+1] with the ky weight -> 96 reads/wave/cc (-33%), same MFMA count.
//   B-loads interleaved per-ky to keep live set ~230 < 256 cap.

#define DEVFN static __device__ __forceinline__

DEVFN float sigmoidf_(float x) { return 1.f / (1.f + expf(-x)); }       // precise
DEVFN float siluf_(float y) { return y / (1.f + __expf(-y)); }          // fast
DEVFN float tanh_fast_(float x) { return 1.f - 2.f / (__expf(2.f * x) + 1.f); }

typedef __attribute__((ext_vector_type(8))) short bf16x8;
typedef __attribute__((ext_vector_type(4))) float f32x4;

DEVFN unsigned short f2bf_(float f) {
    union { __hip_bfloat16 b; unsigned short u; } cv;
    cv.b = __float2bfloat16(f);
    return cv.u;
}
DEVFN float bf2f_(unsigned short u) {
    union { unsigned short u; __hip_bfloat16 b; } cv;
    cv.u = u;
    return __bfloat162float(cv.b);
}

DEVFN void async_cp16(const void* g, void* l) {
    __builtin_amdgcn_global_load_lds(
        (const __attribute__((address_space(1))) unsigned int*)g,
        (__attribute__((address_space(3))) unsigned int*)l, 16, 0, 0);
}

// ================= mega1 v2 =================
// grid layout: [0,16)   langmlp (FIRST so it overlaps the rest, not a tail)
//              [16,1040) wsum: wave w of block handles plane (bid-16)*4+w
//              [1040,1680) prep: 1024 pack-elements per block (4/thread)
#define M1_LANG_END 16
#define M1_WSUM_END 1040
#define M1_GRID     1680

__global__ __launch_bounds__(256) void mega1_kernel(
        const float* __restrict__ Wv, const float* __restrict__ Wf1,
        const float* __restrict__ Wf3, const float* __restrict__ Wf2,
        short* __restrict__ WvB, short* __restrict__ W1B,
        short* __restrict__ W3B, short* __restrict__ WB2,
        float* __restrict__ zbuf,
        const float* __restrict__ img, float* __restrict__ S,
        const float* __restrict__ flang, const int* __restrict__ mask,
        const float* __restrict__ Wm1, const float* __restrict__ bm1,
        const float* __restrict__ Wm2, const float* __restrict__ bm2,
        float* __restrict__ ycxc) {
    __shared__ int   mlds[40];
    __shared__ float inc[40];
    __shared__ float isum;
    __shared__ __attribute__((aligned(16))) float fa[768];
    __shared__ float h[392];
    __shared__ float o16[16];
    int bid = blockIdx.x, t = threadIdx.x;
    int w = t >> 6, lane = t & 63;

    if (bid < M1_LANG_END) {
        // -------- langmlp (coalesced float4 GEMV, shuffle reduce) --------
        int b = bid;
        if (t < 40) mlds[t] = mask[b * 40 + t];
        __syncthreads();
        if (t == 0) {
            float cum = 0.f;
            float tot = 0.f;
            for (int l = 0; l < 40; ++l) tot += (float)mlds[l];
            float sm = 0.f;
            for (int l = 0; l < 40; ++l) {
                float m = (float)mlds[l];
                cum += m;
                float v = (cum > 1.f && cum < tot) ? m : 0.f;
                inc[l] = v; sm += v;
            }
            isum = sm;
        }
        __syncthreads();
        // fa[d] = sum_l flang[b,l,d]*inc[l] / isum   (coalesced over d)
        {
            float rinv = 1.f / isum;
            for (int d = t; d < 768; d += 256) {
                float a = 0.f;
                const float* fp = flang + (size_t)(b * 40) * 768 + d;
                for (int l = 0; l < 40; ++l) a = fmaf(fp[(size_t)l * 768], inc[l], a);
                fa[d] = a * rinv;
            }
        }
        __syncthreads();
        // h[u] = bm1[u] + <fa, Wm1[u,:]>  -- lane-split K, float4, coalesced
        {
            const float4* W14 = (const float4*)Wm1;   // row stride 192 float4
            const float4* fa4 = (const float4*)fa;
            for (int u = w; u < 392; u += 4) {
                float a = 0.f;
#pragma unroll
                for (int j = 0; j < 3; ++j) {
                    float4 wv = W14[(size_t)u * 192 + j * 64 + lane];
                    float4 fv = fa4[j * 64 + lane];
                    a = fmaf(wv.x, fv.x, a);
                    a = fmaf(wv.y, fv.y, a);
                    a = fmaf(wv.z, fv.z, a);
                    a = fmaf(wv.w, fv.w, a);
                }
#pragma unroll
                for (int m = 32; m; m >>= 1) a += __shfl_xor(a, m);
                if (lane == 0) h[u] = a + bm1[u];
            }
        }
        __syncthreads();
        // o16[u2] = sigmoid(bm2[u2] + <h, Wm2[u2,:]>)  -- 4 outputs per wave
        {
#pragma unroll
            for (int q = 0; q < 4; ++q) {
                int u2 = w * 4 + q;
                float a = 0.f;
#pragma unroll
                for (int j = 0; j < 7; ++j) {
                    int k = j * 64 + lane;
                    if (k < 392) a = fmaf(h[k], Wm2[(size_t)u2 * 392 + k], a);
                }
#pragma unroll
                for (int m = 32; m; m >>= 1) a += __shfl_xor(a, m);
                if (lane == 0) o16[u2] = sigmoidf_(a + bm2[u2]);
            }
        }
        __syncthreads();
        if (t < 8) {
            ycxc[b * 8 + t]       = (float)(int)(o16[2 * t] * 64.f);
            ycxc[128 + b * 8 + t] = (float)(int)(o16[2 * t + 1] * 64.f);
        }
    } else if (bid < M1_WSUM_END) {
        // -------- wsum: one wave per (b,ci) plane, float4, shuffle reduce --------
        int bc = (bid - M1_LANG_END) * 4 + w;
        const float4* p4 = (const float4*)(img + (size_t)bc * 4096);
        int lx2 = lane & 15;
        float s[9];
#pragma unroll
        for (int k = 0; k < 9; ++k) s[k] = 0.f;
#pragma unroll
        for (int i = 0; i < 16; ++i) {
            float4 v = p4[lane + i * 64];
            int y = (lane >> 4) + 4 * i;                 // row of this float4
            float sum4 = v.x + v.y + v.z + v.w;
            // horizontal sums restricted to col windows [kx, kx+62)
            float p0 = (lx2 == 15) ? (v.x + v.y) : sum4;                  // cols 0..61
            float p1 = sum4 - ((lx2 == 0) ? v.x : 0.f)
                            - ((lx2 == 15) ? v.w : 0.f);                  // cols 1..62
            float p2 = (lx2 == 0) ? (v.z + v.w) : sum4;                   // cols 2..63
            float ym0 = (y <= 61) ? 1.f : 0.f;
            float ym1 = (y >= 1 && y <= 62) ? 1.f : 0.f;
            float ym2 = (y >= 2) ? 1.f : 0.f;
            s[0] = fmaf(ym0, p0, s[0]); s[1] = fmaf(ym0, p1, s[1]); s[2] = fmaf(ym0, p2, s[2]);
            s[3] = fmaf(ym1, p0, s[3]); s[4] = fmaf(ym1, p1, s[4]); s[5] = fmaf(ym1, p2, s[5]);
            s[6] = fmaf(ym2, p0, s[6]); s[7] = fmaf(ym2, p1, s[7]); s[8] = fmaf(ym2, p2, s[8]);
        }
#pragma unroll
        for (int m = 32; m; m >>= 1)
#pragma unroll
            for (int k = 0; k < 9; ++k) s[k] += __shfl_xor(s[k], m);
        if (lane == 0) {
#pragma unroll
            for (int k = 0; k < 9; ++k) S[(size_t)bc * 9 + k] = s[k];
        }
    } else {
        // -------- prep: weight packing + zero scratch (4 elements/thread) --------
        int base = (bid - M1_WSUM_END) * 1024;
#pragma unroll
        for (int i = 0; i < 4; ++i) {
            int idx = base + i * 256 + t;
            if (idx < 8) zbuf[idx] = 0.f;
            if (idx < 65536) {
                int j    = idx & 7;
                int ln   = (idx >> 3) & 63;
                int coT  = (idx >> 9) & 15;
                int ci32 = (idx >> 13) & 7;
                int co = coT * 16 + (ln & 15);
                int ci = ci32 * 32 + ((ln >> 4) << 3) + j;
                int src = co * 256 + ci;
                WvB[idx] = (short)f2bf_(Wv[src]);
                W1B[idx] = (short)f2bf_(Wf1[src]);
                W3B[idx] = (short)f2bf_(Wf3[src]);
            }
            int oo = idx - 65536;
            if (oo >= 0 && oo < 589824) {
                int j    = oo & 7;
                int ln   = (oo >> 3) & 63;
                int coT  = (oo >> 9) & 15;
                int ci32 = (oo >> 13) & 7;
                int kk   = oo >> 16;
                int co = coT * 16 + (ln & 15);
                int ci = ci32 * 32 + ((ln >> 4) << 3) + j;
                WB2[oo] = (short)f2bf_(Wf2[(co * 256 + ci) * 9 + kk]);
            }
        }
    }
}

// ================= f01': sigw + gauss + Wv GEMM + FiLM + l2norm + Wf1 GEMM =================
__global__ __launch_bounds__(256) void f01_kernel(
        const float* __restrict__ img, const short* __restrict__ wvb,
        const short* __restrict__ w1b,
        const float* __restrict__ sv, const float* __restrict__ bv,
        const float* __restrict__ s1, const float* __restrict__ b1,
        const float* __restrict__ S, const float* __restrict__ Ws,
        const float* __restrict__ bs, const float* __restrict__ ycxc,
        const float* __restrict__ sigma_w,
        const float* __restrict__ Wg, const float* __restrict__ sg,
        const float* __restrict__ bg,
        const float* __restrict__ Wb, const float* __restrict__ sb,
        const float* __restrict__ bb,
        __hip_bfloat16* __restrict__ outB) {
    __shared__ __attribute__((aligned(16))) short lA[64 * 264];   // 33792 B (aliased: red, pr)
    __shared__ float invs[64];
    __shared__ float ls_sv[256], ls_bv[256], ls_s1[256], ls_b1[256];
    __shared__ float ls_g[64], ls_bm[64];
    __shared__ float sigw8[8];
    float* red = (float*)lA;                                       // phase A alias
    float* pr  = (float*)lA;                                       // film alias (sequenced)
    // bijective XCD swizzle: 1024 blocks, 8 XCDs, 128 per XCD contiguous
    int blk0 = blockIdx.x;
    int blk = (blk0 & 7) * 128 + (blk0 >> 3);
    int b = blk >> 6, y = blk & 63;
    int t = threadIdx.x, w = t >> 6, lane = t & 63;
    int lx = lane & 15, koct = lane >> 4;

    ls_sv[t] = sv[t]; ls_bv[t] = bv[t];
    ls_s1[t] = s1[t]; ls_b1[t] = b1[t];

    // ---- phase A: sigw recompute for this b (red aliases lA) ----
    {
        float s9[9];
        const float* Sp = S + (size_t)(b * 256 + t) * 9;
#pragma unroll
        for (int k = 0; k < 9; ++k) s9[k] = Sp[k];
#pragma unroll
        for (int co = 0; co < 8; ++co) {
            const float* wp = Ws + (size_t)(co * 256 + t) * 9;
            float a = 0.f;
#pragma unroll
            for (int k = 0; k < 9; ++k) a = fmaf(wp[k], s9[k], a);
            red[co * 256 + t] = a;
        }
        __syncthreads();
        for (int st = 128; st > 0; st >>= 1) {
            if (t < st) {
#pragma unroll
                for (int co = 0; co < 8; ++co) red[co * 256 + t] += red[co * 256 + t + st];
            }
            __syncthreads();
        }
        if (t < 8) sigw8[t] = sigmoidf_(red[t * 256] / 3844.f + bs[t]);
        __syncthreads();
    }

    // ---- phase B: gaussian -> gamma/beta -> ls_g, ls_bm for this row ----
    if (t < 64) {
        float sx = sigma_w[0] * 64.f;
        float wv8[8];
#pragma unroll
        for (int n = 0; n < 8; ++n) {
            float yc = ycxc[b * 8 + n], xc = ycxc[128 + b * 8 + n];
            float sy = sx * sigw8[n];
            float dy = (float)y - yc, dx = (float)t - xc;
            wv8[n] = expf(-(dy * dy / (2.f * sy * sy) + dx * dx / (2.f * sx * sx)));
        }
        float gacc = 0.f, bmax = -3.4e38f;
#pragma unroll
        for (int n = 0; n < 8; ++n) {
            float a1 = 0.f, a2 = 0.f;
#pragma unroll
            for (int m = 0; m < 8; ++m) {
                a1 = fmaf(Wg[n * 8 + m], wv8[m], a1);
                a2 = fmaf(Wb[n * 8 + m], wv8[m], a2);
            }
            float ga = tanhf(siluf_(a1 * sg[n] + bg[n]));
            float be = tanhf(siluf_(a2 * sb[n] + bb[n]));
            gacc += ga;
            bmax = fmaxf(bmax, be);
        }
        ls_g[t]  = gacc * 0.125f;
        ls_bm[t] = bmax;
    }

    // ---- stage img (fp32 NCHW) -> lA bf16 [x][ci] ----
    {
        int x = t & 63, cg = t >> 6;
        const float* ib = img + (size_t)b * 1048576 + y * 64 + x;
#pragma unroll
        for (int c8 = 0; c8 < 8; ++c8) {
            int ci0 = cg * 64 + c8 * 8;
            unsigned short r[8];
#pragma unroll
            for (int j = 0; j < 8; ++j) r[j] = f2bf_(ib[(size_t)(ci0 + j) * 4096]);
            *(uint4*)&lA[x * 264 + ci0] = *(uint4*)r;
        }
    }
    f32x4 acc[4][4];
#pragma unroll
    for (int mi = 0; mi < 4; ++mi)
#pragma unroll
        for (int ni = 0; ni < 4; ++ni) acc[mi][ni] = (f32x4){0.f, 0.f, 0.f, 0.f};
    __syncthreads();

    // ---- GEMM1: Wv ----
#pragma unroll
    for (int k32 = 0; k32 < 8; ++k32) {
        const short* wp = wvb + (((k32 * 16) + w * 4) * 64 + lane) * 8;
        bf16x8 bfr[4];
#pragma unroll
        for (int ni = 0; ni < 4; ++ni) bfr[ni] = *(const bf16x8*)(wp + ni * 512);
        bf16x8 afr[4];
#pragma unroll
        for (int mi = 0; mi < 4; ++mi)
            afr[mi] = *(const bf16x8*)&lA[(mi * 16 + lx) * 264 + k32 * 32 + koct * 8];
#pragma unroll
        for (int mi = 0; mi < 4; ++mi)
#pragma unroll
            for (int ni = 0; ni < 4; ++ni)
                acc[mi][ni] = __builtin_amdgcn_mfma_f32_16x16x32_bf16(afr[mi], bfr[ni], acc[mi][ni], 0, 0, 0);
    }
    __syncthreads();   // lA (img) dead; pr may now be written

    // ---- FiLM epilogue + partial l2 ----
#pragma unroll
    for (int mi = 0; mi < 4; ++mi)
#pragma unroll
        for (int rr = 0; rr < 4; ++rr) {
            int x = mi * 16 + koct * 4 + rr;
            float ps = 0.f;
#pragma unroll
            for (int ni = 0; ni < 4; ++ni) {
                int co = w * 64 + ni * 16 + lx;
                float yv = fmaf(acc[mi][ni][rr], ls_sv[co], ls_bv[co]);
                float mvv = tanh_fast_(siluf_(yv));
                float v = fmaf(ls_g[x], mvv, ls_bm[x]);
                acc[mi][ni][rr] = v;
                ps += v * v;
            }
            pr[x * 64 + w * 16 + lx] = ps;
        }
    __syncthreads();
    if (t < 64) {
        float s2 = 0.f;
        for (int q = 0; q < 64; ++q) s2 += pr[t * 64 + q];
        invs[t] = 1.f / fmaxf(sqrtf(s2), 1e-12f);
    }
    __syncthreads();   // pr dead; lA may be rewritten (v)

    // ---- v (normalized) -> lA bf16 [x][ci] ----
#pragma unroll
    for (int mi = 0; mi < 4; ++mi)
#pragma unroll
        for (int ni = 0; ni < 4; ++ni) {
            int co = w * 64 + ni * 16 + lx;
#pragma unroll
            for (int rr = 0; rr < 4; ++rr) {
                int x = mi * 16 + koct * 4 + rr;
                lA[x * 264 + co] = (short)f2bf_(acc[mi][ni][rr] * invs[x]);
            }
        }
#pragma unroll
    for (int mi = 0; mi < 4; ++mi)
#pragma unroll
        for (int ni = 0; ni < 4; ++ni) acc[mi][ni] = (f32x4){0.f, 0.f, 0.f, 0.f};
    __syncthreads();

    // ---- GEMM2: Wf1 ----
#pragma unroll
    for (int k32 = 0; k32 < 8; ++k32) {
        const short* wp = w1b + (((k32 * 16) + w * 4) * 64 + lane) * 8;
        bf16x8 bfr[4];
#pragma unroll
        for (int ni = 0; ni < 4; ++ni) bfr[ni] = *(const bf16x8*)(wp + ni * 512);
        bf16x8 afr[4];
#pragma unroll
        for (int mi = 0; mi < 4; ++mi)
            afr[mi] = *(const bf16x8*)&lA[(mi * 16 + lx) * 264 + k32 * 32 + koct * 8];
#pragma unroll
        for (int mi = 0; mi < 4; ++mi)
#pragma unroll
            for (int ni = 0; ni < 4; ++ni)
                acc[mi][ni] = __builtin_amdgcn_mfma_f32_16x16x32_bf16(afr[mi], bfr[ni], acc[mi][ni], 0, 0, 0);
    }
    __syncthreads();

    // ---- silu -> lA [x][co] -> NHWC store ----
#pragma unroll
    for (int mi = 0; mi < 4; ++mi)
#pragma unroll
        for (int ni = 0; ni < 4; ++ni) {
            int co = w * 64 + ni * 16 + lx;
#pragma unroll
            for (int rr = 0; rr < 4; ++rr) {
                int x = mi * 16 + koct * 4 + rr;
                float yv = fmaf(acc[mi][ni][rr], ls_s1[co], ls_b1[co]);
                lA[x * 264 + co] = (short)f2bf_(siluf_(yv));
            }
        }
    __syncthreads();
    unsigned short* og = (unsigned short*)outB + (size_t)(b * 64 + y) * 16384;
#pragma unroll
    for (int it = 0; it < 8; ++it) {
        int e8 = t + it * 256;
        int x2 = e8 >> 5, c8 = e8 & 31;
        *(uint4*)(og + e8 * 8) = *(uint4*)&lA[x2 * 264 + c8 * 8];
    }
}

// ================= c3f: conv3x3 (async dbuf, row-shared A loads) + Wf3 GEMM + v_add + l2norm =================
DEVFN void stage_chunk(const unsigned short* __restrict__ xg, short* ldsbuf,
                       const unsigned short* __restrict__ zbuf, int cc, int y0, int t) {
#pragma unroll
    for (int p = 0; p < 10; ++p) {
        int slot = t + p * 256;
        if (slot < 2376) {                       // 4 rows * 66 xp * 9
            int r = slot / 594;
            int rem = slot - r * 594;
            int xp = rem / 9;
            int oct = rem - xp * 9;
            int ys = y0 + r - 1, xs = xp - 1;
            bool valid = (oct < 8) && (ys >= 0) && (ys < 64) && (xs >= 0) && (xs < 64);
            const unsigned short* gp = valid ? (xg + ((ys * 64 + xs) * 256 + cc * 64 + oct * 8))
                                             : zbuf;
            async_cp16(gp, ldsbuf + slot * 8);
        }
    }
}

__global__ __launch_bounds__(256, 2) void c3f_kernel(const __hip_bfloat16* __restrict__ xin,
                                                     const short* __restrict__ wb,
                                                     const float* __restrict__ sc,
                                                     const float* __restrict__ bi,
                                                     const float* __restrict__ zbufF,
                                                     const short* __restrict__ w3b,
                                                     const float* __restrict__ bf3,
                                                     const float* __restrict__ img,
                                                     const float* __restrict__ addw,
                                                     float* __restrict__ outF) {
    __shared__ __attribute__((aligned(16))) short lds[2][19008];   // 2 x 38016 B
    __shared__ float pr2[256];
    __shared__ float invs[64];
    __shared__ float ls_b3[256];
    // bijective XCD swizzle: 512 blocks, 8 XCDs, 64 per XCD contiguous
    int blk0 = blockIdx.x;
    int blk = (blk0 & 7) * 64 + (blk0 >> 3);
    int b = blk >> 5, y0 = (blk & 31) * 2;
    int t = threadIdx.x;
    int w = t >> 6, lane = t & 63;
    int lx = lane & 15, koct = lane >> 4;
    const unsigned short* xg = (const unsigned short*)xin + (size_t)b * 1048576;
    const unsigned short* zbuf = (const unsigned short*)zbufF;
    ls_b3[t] = bf3[t];

    f32x4 acc[8][4];
#pragma unroll
    for (int mi = 0; mi < 8; ++mi)
#pragma unroll
        for (int ni = 0; ni < 4; ++ni) acc[mi][ni] = (f32x4){0.f, 0.f, 0.f, 0.f};

    stage_chunk(xg, lds[0], zbuf, 0, y0, t);
    __syncthreads();

    for (int cc = 0; cc < 4; ++cc) {        // ci chunks of 64
        short* cur = lds[cc & 1];
        if (cc < 3) stage_chunk(xg, lds[(cc + 1) & 1], zbuf, cc + 1, y0, t);
        for (int kx = 0; kx < 3; ++kx) {
            for (int k32 = 0; k32 < 2; ++k32) {
                // A-fragments: 4 input rows x 4 x-blocks, loaded ONCE per (kx,k32).
                // Row r serves output half h at tap ky whenever r = h + ky.
                const short* ab = &cur[(lx + kx) * 72 + k32 * 32 + koct * 8];
                bf16x8 A0[4], A1[4], A2[4], A3[4];
#pragma unroll
                for (int xb = 0; xb < 4; ++xb) A0[xb] = *(const bf16x8*)(ab + (0 * 66 + xb * 16) * 72);
#pragma unroll
                for (int xb = 0; xb < 4; ++xb) A1[xb] = *(const bf16x8*)(ab + (1 * 66 + xb * 16) * 72);
                // ky = 0 weights
                bf16x8 B0[4];
                {
                    const short* wp = wb + (((kx * 8 + cc * 2 + k32) * 16 + w * 4) * 64 + lane) * 8;
#pragma unroll
                    for (int ni = 0; ni < 4; ++ni) B0[ni] = *(const bf16x8*)(wp + ni * 512);
                }
#pragma unroll
                for (int xb = 0; xb < 4; ++xb) A2[xb] = *(const bf16x8*)(ab + (2 * 66 + xb * 16) * 72);
#pragma unroll
                for (int xb = 0; xb < 4; ++xb) A3[xb] = *(const bf16x8*)(ab + (3 * 66 + xb * 16) * 72);
                // ky = 0: half0 <- A0, half1 <- A1
#pragma unroll
                for (int xb = 0; xb < 4; ++xb)
#pragma unroll
                    for (int ni = 0; ni < 4; ++ni) {
                        acc[xb][ni]     = __builtin_amdgcn_mfma_f32_16x16x32_bf16(A0[xb], B0[ni], acc[xb][ni], 0, 0, 0);
                        acc[4 + xb][ni] = __builtin_amdgcn_mfma_f32_16x16x32_bf16(A1[xb], B0[ni], acc[4 + xb][ni], 0, 0, 0);
                    }
                // ky = 1 weights, then half0 <- A1, half1 <- A2
                bf16x8 B1[4];
                {
                    const short* wp = wb + ((((3 + kx) * 8 + cc * 2 + k32) * 16 + w * 4) * 64 + lane) * 8;
#pragma unroll
                    for (int ni = 0; ni < 4; ++ni) B1[ni] = *(const bf16x8*)(wp + ni * 512);
                }
#pragma unroll
                for (int xb = 0; xb < 4; ++xb)
#pragma unroll
                    for (int ni = 0; ni < 4; ++ni) {
                        acc[xb][ni]     = __builtin_amdgcn_mfma_f32_16x16x32_bf16(A1[xb], B1[ni], acc[xb][ni], 0, 0, 0);
                        acc[4 + xb][ni] = __builtin_amdgcn_mfma_f32_16x16x32_bf16(A2[xb], B1[ni], acc[4 + xb][ni], 0, 0, 0);
                    }
                // ky = 2 weights, then half0 <- A2, half1 <- A3
                bf16x8 B2[4];
                {
                    const short* wp = wb + ((((6 + kx) * 8 + cc * 2 + k32) * 16 + w * 4) * 64 + lane) * 8;
#pragma unroll
                    for (int ni = 0; ni < 4; ++ni) B2[ni] = *(const bf16x8*)(wp + ni * 512);
                }
#pragma unroll
                for (int xb = 0; xb < 4; ++xb)
#pragma unroll
                    for (int ni = 0; ni < 4; ++ni) {
                        acc[xb][ni]     = __builtin_amdgcn_mfma_f32_16x16x32_bf16(A2[xb], B2[ni], acc[xb][ni], 0, 0, 0);
                        acc[4 + xb][ni] = __builtin_amdgcn_mfma_f32_16x16x32_bf16(A3[xb], B2[ni], acc[4 + xb][ni], 0, 0, 0);
                    }
            }
        }
        __syncthreads();
    }

    // ---- fused final: per row, Wf3 GEMM from LDS restage + v_add + l2norm ----
    float aw = tanhf(addw[0]);
    float ca = 1.f + aw, cb = 1.f - aw;
    short* ep  = &lds[0][0];    // f2 bf16 [x][ci], stride 264
    short* wst = &lds[1][0];    // w  bf16 [co][x], stride 66
#pragma unroll
    for (int r2 = 0; r2 < 2; ++r2) {
        // f2 row: silu(acc*sc+bi) -> ep [x][ci]
#pragma unroll
        for (int mi4 = 0; mi4 < 4; ++mi4) {
            int mi = r2 * 4 + mi4;
#pragma unroll
            for (int ni = 0; ni < 4; ++ni) {
                int co = w * 64 + ni * 16 + lx;
                float s = sc[co], bb2 = bi[co];
#pragma unroll
                for (int rr = 0; rr < 4; ++rr) {
                    int x = mi4 * 16 + koct * 4 + rr;
                    float yv = fmaf(acc[mi][ni][rr], s, bb2);
                    ep[x * 264 + co] = (short)f2bf_(siluf_(yv));
                }
            }
        }
        __syncthreads();
        // GEMM2: Wf3 on this row
        f32x4 acc2[4][4];
#pragma unroll
        for (int mi = 0; mi < 4; ++mi)
#pragma unroll
            for (int ni = 0; ni < 4; ++ni) acc2[mi][ni] = (f32x4){0.f, 0.f, 0.f, 0.f};
#pragma unroll
        for (int k32 = 0; k32 < 8; ++k32) {
            const short* wp = w3b + (((k32 * 16) + w * 4) * 64 + lane) * 8;
            bf16x8 bfr[4];
#pragma unroll
            for (int ni = 0; ni < 4; ++ni) bfr[ni] = *(const bf16x8*)(wp + ni * 512);
            bf16x8 afr[4];
#pragma unroll
            for (int mi = 0; mi < 4; ++mi)
                afr[mi] = *(const bf16x8*)&ep[(mi * 16 + lx) * 264 + k32 * 32 + koct * 8];
#pragma unroll
            for (int mi = 0; mi < 4; ++mi)
#pragma unroll
                for (int ni = 0; ni < 4; ++ni)
                    acc2[mi][ni] = __builtin_amdgcn_mfma_f32_16x16x32_bf16(afr[mi], bfr[ni], acc2[mi][ni], 0, 0, 0);
        }
        // w = acc2 + bf3 -> wst bf16 [co][x] (v_film << img; bf16 ok)
#pragma unroll
        for (int mi = 0; mi < 4; ++mi)
#pragma unroll
            for (int ni = 0; ni < 4; ++ni) {
                int co = w * 64 + ni * 16 + lx;
                float b3 = ls_b3[co];
#pragma unroll
                for (int rr = 0; rr < 4; ++rr) {
                    int x = mi * 16 + koct * 4 + rr;
                    wst[co * 66 + x] = (short)f2bf_(acc2[mi][ni][rr] + b3);
                }
            }
        __syncthreads();
        // coalesced two-pass: v = ca*img + cb*w ; l2norm over co ; store fp32 NCHW
        int x = t & 63, cg = t >> 6;
        const float* ip = img + (size_t)b * 1048576 + (size_t)(y0 + r2) * 64 + x;
        float ss = 0.f;
#pragma unroll 8
        for (int j = 0; j < 64; ++j) {
            int co = cg * 64 + j;
            float v = fmaf(cb, bf2f_((unsigned short)wst[co * 66 + x]), ca * ip[(size_t)co * 4096]);
            ss += v * v;
        }
        pr2[cg * 64 + x] = ss;
        __syncthreads();
        if (t < 64)
            invs[t] = 1.f / fmaxf(sqrtf(pr2[t] + pr2[64 + t] + pr2[128 + t] + pr2[192 + t]), 1e-12f);
        __syncthreads();
        float iv = invs[x];
        float* op = outF + (size_t)b * 1048576 + (size_t)(y0 + r2) * 64 + x;
#pragma unroll 8
        for (int j = 0; j < 64; ++j) {
            int co = cg * 64 + j;
            float v = fmaf(cb, bf2f_((unsigned short)wst[co * 66 + x]), ca * ip[(size_t)co * 4096]);
            op[(size_t)co * 4096] = v * iv;
        }
        __syncthreads();
    }
}

// ---------------- launch ----------------
extern "C" void kernel_launch(void* const* d_in, const int* in_sizes, int n_in,
                              void* d_out, int out_size, void* d_ws, size_t ws_size,
                              hipStream_t stream) {
    const float* img     = (const float*)d_in[0];
    const float* flang   = (const float*)d_in[1];
    const int*   wmask   = (const int*)d_in[2];
    const float* sigma_w = (const float*)d_in[3];
    const float* W1      = (const float*)d_in[4];
    const float* b1      = (const float*)d_in[5];
    const float* W2      = (const float*)d_in[6];
    const float* b2      = (const float*)d_in[7];
    const float* Wv      = (const float*)d_in[8];
    const float* sv      = (const float*)d_in[9];
    const float* bv      = (const float*)d_in[10];
    const float* Wg      = (const float*)d_in[11];
    const float* sg      = (const float*)d_in[12];
    const float* bg      = (const float*)d_in[13];
    const float* Wb      = (const float*)d_in[14];
    const float* sb      = (const float*)d_in[15];
    const float* bb      = (const float*)d_in[16];
    const float* Wf1     = (const float*)d_in[17];
    const float* sf1     = (const float*)d_in[18];
    const float* bf1     = (const float*)d_in[19];
    const float* Wf2     = (const float*)d_in[20];
    const float* sf2     = (const float*)d_in[21];
    const float* bf2     = (const float*)d_in[22];
    const float* Wf3     = (const float*)d_in[23];
    const float* bf3     = (const float*)d_in[24];
    const float* Ws      = (const float*)d_in[25];
    const float* bs      = (const float*)d_in[26];
    const float* addw    = (const float*)d_in[27];
    float* out = (float*)d_out;
    float* ws  = (float*)d_ws;

    // workspace layout (float offsets)
    short* WvB  = (short*)ws;                     // 32768 f
    short* W1B  = (short*)(ws + 32768);           // 32768 f
    short* W3B  = (short*)(ws + 65536);           // 32768 f
    short* WB2  = (short*)(ws + 98304);           // 294912 f -> ends 393216
    float* ycxc = ws + 393216;                    // 256
    float* S    = ws + 393472;                    // 36864 -> ends 430336
    float* zbuf = ws + 430336;                    // 16 (zeros, written by mega1 prep)
    __hip_bfloat16* bufB = (__hip_bfloat16*)(ws + 430352);   // 16.78M bf16 NHWC

    // 1) langmlp (first, overlaps) + wsum (wave/plane) + prep
    mega1_kernel<<<M1_GRID, 256, 0, stream>>>(Wv, Wf1, Wf3, Wf2, WvB, W1B, W3B, WB2, zbuf,
                                              img, S, flang, wmask, W1, b1, W2, b2, ycxc);
    // 2) f1 = silu(Wf1 * l2norm(g*tanh(silu(Wv*img*sv+bv)) + bmax) * sf1 + bf1)  (sigw+gauss inline)
    f01_kernel<<<1024, 256, 0, stream>>>(img, WvB, W1B, sv, bv, sf1, bf1,
                                         S, Ws, bs, ycxc, sigma_w,
                                         Wg, sg, bg, Wb, sb, bb, bufB);
    // 3) f2 = silu(Wf2(3x3)*f1) ; out = l2norm((1+aw)*img + (1-aw)*(Wf3*f2 + bf3))
    c3f_kernel<<<512, 256, 0, stream>>>(bufB, WB2, sf2, bf2, zbuf, W3B, bf3, img, addw, out);
}

// Round 6
// 400.137 us; speedup vs baseline: 1.3127x; 1.3127x over previous
//
#include <hip/hip_runtime.h>
#include <hip/hip_bf16.h>

// Problem: B=16, C=256, H=64, L=40, TD=768, NC=8, EMB=392
// R7: dispatch-count collapse 8 -> 3 (measured ~15-20us per-dispatch overhead).
// R8: mega1 restructure (langmlp first, wave-per-plane wsum). mega1 115 -> off top-5.
// R9: FAILED (456us): launch_bounds(512,4) reg cap -> scratch spills.
// R10: R8 structure + bijective XCD swizzle. FETCH 108->85MB, dur 112->109. BEST: 403us.
// R11: FAILED (423us): full kk-unroll -> spills (WRITE 65->127MB).
// R12: FAILED (525us): row-shared A-loads -> spills (WRITE 65->83MB). Lesson x3: c3f's
//   acc[8][4]=128 regs leaves no headroom; R10's runtime-kk loop is the feasible schedule.
// R13: c3f = exact R10. f01 phase-A fix: Ws reads were stride-36B gathers (64 lines per
//   load instr, 72 instrs/thread, x1024 blocks, 64x redundant per b) + 8-barrier tree.
//   Moved the Ws dot into mega1's wsum (all lanes hold s[0..8] post-butterfly; lanes 0-7
//   write po[co][b][ci] partials into the old S region). f01 phase A = 8 coalesced loads
//   + wave butterfly + 2 barriers. Zero workspace growth, no atomics, deterministic.

#define DEVFN static __device__ __forceinline__

DEVFN float sigmoidf_(float x) { return 1.f / (1.f + expf(-x)); }       // precise
DEVFN float siluf_(float y) { return y / (1.f + __expf(-y)); }          // fast
DEVFN float tanh_fast_(float x) { return 1.f - 2.f / (__expf(2.f * x) + 1.f); }

typedef __attribute__((ext_vector_type(8))) short bf16x8;
typedef __attribute__((ext_vector_type(4))) float f32x4;

DEVFN unsigned short f2bf_(float f) {
    union { __hip_bfloat16 b; unsigned short u; } cv;
    cv.b = __float2bfloat16(f);
    return cv.u;
}
DEVFN float bf2f_(unsigned short u) {
    union { unsigned short u; __hip_bfloat16 b; } cv;
    cv.u = u;
    return __bfloat162float(cv.b);
}

DEVFN void async_cp16(const void* g, void* l) {
    __builtin_amdgcn_global_load_lds(
        (const __attribute__((address_space(1))) unsigned int*)g,
        (__attribute__((address_space(3))) unsigned int*)l, 16, 0, 0);
}

// ================= mega1 v3 =================
// grid layout: [0,16)   langmlp (FIRST so it overlaps the rest, not a tail)
//              [16,1040) wsum: wave w of block handles plane (bid-16)*4+w
//                        + fused Ws-dot partials -> po[co][b][ci]
//              [1040,1680) prep: 1024 pack-elements per block (4/thread)
#define M1_LANG_END 16
#define M1_WSUM_END 1040
#define M1_GRID     1680

__global__ __launch_bounds__(256) void mega1_kernel(
        const float* __restrict__ Wv, const float* __restrict__ Wf1,
        const float* __restrict__ Wf3, const float* __restrict__ Wf2,
        short* __restrict__ WvB, short* __restrict__ W1B,
        short* __restrict__ W3B, short* __restrict__ WB2,
        float* __restrict__ zbuf,
        const float* __restrict__ img, float* __restrict__ po,
        const float* __restrict__ Ws,
        const float* __restrict__ flang, const int* __restrict__ mask,
        const float* __restrict__ Wm1, const float* __restrict__ bm1,
        const float* __restrict__ Wm2, const float* __restrict__ bm2,
        float* __restrict__ ycxc) {
    __shared__ int   mlds[40];
    __shared__ float inc[40];
    __shared__ float isum;
    __shared__ __attribute__((aligned(16))) float fa[768];
    __shared__ float h[392];
    __shared__ float o16[16];
    int bid = blockIdx.x, t = threadIdx.x;
    int w = t >> 6, lane = t & 63;

    if (bid < M1_LANG_END) {
        // -------- langmlp (coalesced float4 GEMV, shuffle reduce) --------
        int b = bid;
        if (t < 40) mlds[t] = mask[b * 40 + t];
        __syncthreads();
        if (t == 0) {
            float cum = 0.f;
            float tot = 0.f;
            for (int l = 0; l < 40; ++l) tot += (float)mlds[l];
            float sm = 0.f;
            for (int l = 0; l < 40; ++l) {
                float m = (float)mlds[l];
                cum += m;
                float v = (cum > 1.f && cum < tot) ? m : 0.f;
                inc[l] = v; sm += v;
            }
            isum = sm;
        }
        __syncthreads();
        // fa[d] = sum_l flang[b,l,d]*inc[l] / isum   (coalesced over d)
        {
            float rinv = 1.f / isum;
            for (int d = t; d < 768; d += 256) {
                float a = 0.f;
                const float* fp = flang + (size_t)(b * 40) * 768 + d;
                for (int l = 0; l < 40; ++l) a = fmaf(fp[(size_t)l * 768], inc[l], a);
                fa[d] = a * rinv;
            }
        }
        __syncthreads();
        // h[u] = bm1[u] + <fa, Wm1[u,:]>  -- lane-split K, float4, coalesced
        {
            const float4* W14 = (const float4*)Wm1;   // row stride 192 float4
            const float4* fa4 = (const float4*)fa;
            for (int u = w; u < 392; u += 4) {
                float a = 0.f;
#pragma unroll
                for (int j = 0; j < 3; ++j) {
                    float4 wv = W14[(size_t)u * 192 + j * 64 + lane];
                    float4 fv = fa4[j * 64 + lane];
                    a = fmaf(wv.x, fv.x, a);
                    a = fmaf(wv.y, fv.y, a);
                    a = fmaf(wv.z, fv.z, a);
                    a = fmaf(wv.w, fv.w, a);
                }
#pragma unroll
                for (int m = 32; m; m >>= 1) a += __shfl_xor(a, m);
                if (lane == 0) h[u] = a + bm1[u];
            }
        }
        __syncthreads();
        // o16[u2] = sigmoid(bm2[u2] + <h, Wm2[u2,:]>)  -- 4 outputs per wave
        {
#pragma unroll
            for (int q = 0; q < 4; ++q) {
                int u2 = w * 4 + q;
                float a = 0.f;
#pragma unroll
                for (int j = 0; j < 7; ++j) {
                    int k = j * 64 + lane;
                    if (k < 392) a = fmaf(h[k], Wm2[(size_t)u2 * 392 + k], a);
                }
#pragma unroll
                for (int m = 32; m; m >>= 1) a += __shfl_xor(a, m);
                if (lane == 0) o16[u2] = sigmoidf_(a + bm2[u2]);
            }
        }
        __syncthreads();
        if (t < 8) {
            ycxc[b * 8 + t]       = (float)(int)(o16[2 * t] * 64.f);
            ycxc[128 + b * 8 + t] = (float)(int)(o16[2 * t + 1] * 64.f);
        }
    } else if (bid < M1_WSUM_END) {
        // -------- wsum: one wave per (b,ci) plane, float4, shuffle reduce --------
        int bc = (bid - M1_LANG_END) * 4 + w;
        const float4* p4 = (const float4*)(img + (size_t)bc * 4096);
        int lx2 = lane & 15;
        float s[9];
#pragma unroll
        for (int k = 0; k < 9; ++k) s[k] = 0.f;
#pragma unroll
        for (int i = 0; i < 16; ++i) {
            float4 v = p4[lane + i * 64];
            int y = (lane >> 4) + 4 * i;                 // row of this float4
            float sum4 = v.x + v.y + v.z + v.w;
            // horizontal sums restricted to col windows [kx, kx+62)
            float p0 = (lx2 == 15) ? (v.x + v.y) : sum4;                  // cols 0..61
            float p1 = sum4 - ((lx2 == 0) ? v.x : 0.f)
                            - ((lx2 == 15) ? v.w : 0.f);                  // cols 1..62
            float p2 = (lx2 == 0) ? (v.z + v.w) : sum4;                   // cols 2..63
            float ym0 = (y <= 61) ? 1.f : 0.f;
            float ym1 = (y >= 1 && y <= 62) ? 1.f : 0.f;
            float ym2 = (y >= 2) ? 1.f : 0.f;
            s[0] = fmaf(ym0, p0, s[0]); s[1] = fmaf(ym0, p1, s[1]); s[2] = fmaf(ym0, p2, s[2]);
            s[3] = fmaf(ym1, p0, s[3]); s[4] = fmaf(ym1, p1, s[4]); s[5] = fmaf(ym1, p2, s[5]);
            s[6] = fmaf(ym2, p0, s[6]); s[7] = fmaf(ym2, p1, s[7]); s[8] = fmaf(ym2, p2, s[8]);
        }
#pragma unroll
        for (int m = 32; m; m >>= 1)
#pragma unroll
            for (int k = 0; k < 9; ++k) s[k] += __shfl_xor(s[k], m);
        // all lanes now hold the full 9 window sums; lanes 0..7 fuse the Ws dot
        {
            int b8 = bc >> 8, ci = bc & 255;
            if (lane < 8) {
                const float* wp = Ws + (size_t)(lane * 256 + ci) * 9;
                float a = 0.f;
#pragma unroll
                for (int k = 0; k < 9; ++k) a = fmaf(wp[k], s[k], a);
                po[(size_t)(lane * 16 + b8) * 256 + ci] = a;
            }
        }
    } else {
        // -------- prep: weight packing + zero scratch (4 elements/thread) --------
        int base = (bid - M1_WSUM_END) * 1024;
#pragma unroll
        for (int i = 0; i < 4; ++i) {
            int idx = base + i * 256 + t;
            if (idx < 8) zbuf[idx] = 0.f;
            if (idx < 65536) {
                int j    = idx & 7;
                int ln   = (idx >> 3) & 63;
                int coT  = (idx >> 9) & 15;
                int ci32 = (idx >> 13) & 7;
                int co = coT * 16 + (ln & 15);
                int ci = ci32 * 32 + ((ln >> 4) << 3) + j;
                int src = co * 256 + ci;
                WvB[idx] = (short)f2bf_(Wv[src]);
                W1B[idx] = (short)f2bf_(Wf1[src]);
                W3B[idx] = (short)f2bf_(Wf3[src]);
            }
            int oo = idx - 65536;
            if (oo >= 0 && oo < 589824) {
                int j    = oo & 7;
                int ln   = (oo >> 3) & 63;
                int coT  = (oo >> 9) & 15;
                int ci32 = (oo >> 13) & 7;
                int kk   = oo >> 16;
                int co = coT * 16 + (ln & 15);
                int ci = ci32 * 32 + ((ln >> 4) << 3) + j;
                WB2[oo] = (short)f2bf_(Wf2[(co * 256 + ci) * 9 + kk]);
            }
        }
    }
}

// ================= f01': sigw (from po partials) + gauss + Wv GEMM + FiLM + l2norm + Wf1 GEMM =================
__global__ __launch_bounds__(256) void f01_kernel(
        const float* __restrict__ img, const short* __restrict__ wvb,
        const short* __restrict__ w1b,
        const float* __restrict__ sv, const float* __restrict__ bv,
        const float* __restrict__ s1, const float* __restrict__ b1,
        const float* __restrict__ po,
        const float* __restrict__ bs, const float* __restrict__ ycxc,
        const float* __restrict__ sigma_w,
        const float* __restrict__ Wg, const float* __restrict__ sg,
        const float* __restrict__ bg,
        const float* __restrict__ Wb, const float* __restrict__ sb,
        const float* __restrict__ bb,
        __hip_bfloat16* __restrict__ outB) {
    __shared__ __attribute__((aligned(16))) short lA[64 * 264];   // 33792 B (aliased: pr)
    __shared__ float invs[64];
    __shared__ float ls_sv[256], ls_bv[256], ls_s1[256], ls_b1[256];
    __shared__ float ls_g[64], ls_bm[64];
    __shared__ float sigw8[8];
    __shared__ float redw[32];
    float* pr  = (float*)lA;                                       // film alias (sequenced)
    // bijective XCD swizzle: 1024 blocks, 8 XCDs, 128 per XCD contiguous
    int blk0 = blockIdx.x;
    int blk = (blk0 & 7) * 128 + (blk0 >> 3);
    int b = blk >> 6, y = blk & 63;
    int t = threadIdx.x, w = t >> 6, lane = t & 63;
    int lx = lane & 15, koct = lane >> 4;

    ls_sv[t] = sv[t]; ls_bv[t] = bv[t];
    ls_s1[t] = s1[t]; ls_b1[t] = b1[t];

    // ---- phase A: sigw from po partials (8 coalesced loads + wave butterfly) ----
    {
        float a8[8];
#pragma unroll
        for (int co = 0; co < 8; ++co) a8[co] = po[(size_t)(co * 16 + b) * 256 + t];
#pragma unroll
        for (int m = 32; m; m >>= 1)
#pragma unroll
            for (int co = 0; co < 8; ++co) a8[co] += __shfl_xor(a8[co], m);
        if (lane == 0) {
#pragma unroll
            for (int co = 0; co < 8; ++co) redw[w * 8 + co] = a8[co];
        }
        __syncthreads();
        if (t < 8) sigw8[t] = sigmoidf_((redw[t] + redw[8 + t] + redw[16 + t] + redw[24 + t]) / 3844.f + bs[t]);
        __syncthreads();
    }

    // ---- phase B: gaussian -> gamma/beta -> ls_g, ls_bm for this row ----
    if (t < 64) {
        float sx = sigma_w[0] * 64.f;
        float wv8[8];
#pragma unroll
        for (int n = 0; n < 8; ++n) {
            float yc = ycxc[b * 8 + n], xc = ycxc[128 + b * 8 + n];
            float sy = sx * sigw8[n];
            float dy = (float)y - yc, dx = (float)t - xc;
            wv8[n] = expf(-(dy * dy / (2.f * sy * sy) + dx * dx / (2.f * sx * sx)));
        }
        float gacc = 0.f, bmax = -3.4e38f;
#pragma unroll
        for (int n = 0; n < 8; ++n) {
            float a1 = 0.f, a2 = 0.f;
#pragma unroll
            for (int m = 0; m < 8; ++m) {
                a1 = fmaf(Wg[n * 8 + m], wv8[m], a1);
                a2 = fmaf(Wb[n * 8 + m], wv8[m], a2);
            }
            float ga = tanhf(siluf_(a1 * sg[n] + bg[n]));
            float be = tanhf(siluf_(a2 * sb[n] + bb[n]));
            gacc += ga;
            bmax = fmaxf(bmax, be);
        }
        ls_g[t]  = gacc * 0.125f;
        ls_bm[t] = bmax;
    }

    // ---- stage img (fp32 NCHW) -> lA bf16 [x][ci] ----
    {
        int x = t & 63, cg = t >> 6;
        const float* ib = img + (size_t)b * 1048576 + y * 64 + x;
#pragma unroll
        for (int c8 = 0; c8 < 8; ++c8) {
            int ci0 = cg * 64 + c8 * 8;
            unsigned short r[8];
#pragma unroll
            for (int j = 0; j < 8; ++j) r[j] = f2bf_(ib[(size_t)(ci0 + j) * 4096]);
            *(uint4*)&lA[x * 264 + ci0] = *(uint4*)r;
        }
    }
    f32x4 acc[4][4];
#pragma unroll
    for (int mi = 0; mi < 4; ++mi)
#pragma unroll
        for (int ni = 0; ni < 4; ++ni) acc[mi][ni] = (f32x4){0.f, 0.f, 0.f, 0.f};
    __syncthreads();

    // ---- GEMM1: Wv ----
#pragma unroll
    for (int k32 = 0; k32 < 8; ++k32) {
        const short* wp = wvb + (((k32 * 16) + w * 4) * 64 + lane) * 8;
        bf16x8 bfr[4];
#pragma unroll
        for (int ni = 0; ni < 4; ++ni) bfr[ni] = *(const bf16x8*)(wp + ni * 512);
        bf16x8 afr[4];
#pragma unroll
        for (int mi = 0; mi < 4; ++mi)
            afr[mi] = *(const bf16x8*)&lA[(mi * 16 + lx) * 264 + k32 * 32 + koct * 8];
#pragma unroll
        for (int mi = 0; mi < 4; ++mi)
#pragma unroll
            for (int ni = 0; ni < 4; ++ni)
                acc[mi][ni] = __builtin_amdgcn_mfma_f32_16x16x32_bf16(afr[mi], bfr[ni], acc[mi][ni], 0, 0, 0);
    }
    __syncthreads();   // lA (img) dead; pr may now be written

    // ---- FiLM epilogue + partial l2 ----
#pragma unroll
    for (int mi = 0; mi < 4; ++mi)
#pragma unroll
        for (int rr = 0; rr < 4; ++rr) {
            int x = mi * 16 + koct * 4 + rr;
            float ps = 0.f;
#pragma unroll
            for (int ni = 0; ni < 4; ++ni) {
                int co = w * 64 + ni * 16 + lx;
                float yv = fmaf(acc[mi][ni][rr], ls_sv[co], ls_bv[co]);
                float mvv = tanh_fast_(siluf_(yv));
                float v = fmaf(ls_g[x], mvv, ls_bm[x]);
                acc[mi][ni][rr] = v;
                ps += v * v;
            }
            pr[x * 64 + w * 16 + lx] = ps;
        }
    __syncthreads();
    if (t < 64) {
        float s2 = 0.f;
        for (int q = 0; q < 64; ++q) s2 += pr[t * 64 + q];
        invs[t] = 1.f / fmaxf(sqrtf(s2), 1e-12f);
    }
    __syncthreads();   // pr dead; lA may be rewritten (v)

    // ---- v (normalized) -> lA bf16 [x][ci] ----
#pragma unroll
    for (int mi = 0; mi < 4; ++mi)
#pragma unroll
        for (int ni = 0; ni < 4; ++ni) {
            int co = w * 64 + ni * 16 + lx;
#pragma unroll
            for (int rr = 0; rr < 4; ++rr) {
                int x = mi * 16 + koct * 4 + rr;
                lA[x * 264 + co] = (short)f2bf_(acc[mi][ni][rr] * invs[x]);
            }
        }
#pragma unroll
    for (int mi = 0; mi < 4; ++mi)
#pragma unroll
        for (int ni = 0; ni < 4; ++ni) acc[mi][ni] = (f32x4){0.f, 0.f, 0.f, 0.f};
    __syncthreads();

    // ---- GEMM2: Wf1 ----
#pragma unroll
    for (int k32 = 0; k32 < 8; ++k32) {
        const short* wp = w1b + (((k32 * 16) + w * 4) * 64 + lane) * 8;
        bf16x8 bfr[4];
#pragma unroll
        for (int ni = 0; ni < 4; ++ni) bfr[ni] = *(const bf16x8*)(wp + ni * 512);
        bf16x8 afr[4];
#pragma unroll
        for (int mi = 0; mi < 4; ++mi)
            afr[mi] = *(const bf16x8*)&lA[(mi * 16 + lx) * 264 + k32 * 32 + koct * 8];
#pragma unroll
        for (int mi = 0; mi < 4; ++mi)
#pragma unroll
            for (int ni = 0; ni < 4; ++ni)
                acc[mi][ni] = __builtin_amdgcn_mfma_f32_16x16x32_bf16(afr[mi], bfr[ni], acc[mi][ni], 0, 0, 0);
    }
    __syncthreads();

    // ---- silu -> lA [x][co] -> NHWC store ----
#pragma unroll
    for (int mi = 0; mi < 4; ++mi)
#pragma unroll
        for (int ni = 0; ni < 4; ++ni) {
            int co = w * 64 + ni * 16 + lx;
#pragma unroll
            for (int rr = 0; rr < 4; ++rr) {
                int x = mi * 16 + koct * 4 + rr;
                float yv = fmaf(acc[mi][ni][rr], ls_s1[co], ls_b1[co]);
                lA[x * 264 + co] = (short)f2bf_(siluf_(yv));
            }
        }
    __syncthreads();
    unsigned short* og = (unsigned short*)outB + (size_t)(b * 64 + y) * 16384;
#pragma unroll
    for (int it = 0; it < 8; ++it) {
        int e8 = t + it * 256;
        int x2 = e8 >> 5, c8 = e8 & 31;
        *(uint4*)(og + e8 * 8) = *(uint4*)&lA[x2 * 264 + c8 * 8];
    }
}

// ================= c3f: conv3x3 (async dbuf) + Wf3 GEMM + v_add + l2norm =================
DEVFN void stage_chunk(const unsigned short* __restrict__ xg, short* ldsbuf,
                       const unsigned short* __restrict__ zbuf, int cc, int y0, int t) {
#pragma unroll
    for (int p = 0; p < 10; ++p) {
        int slot = t + p * 256;
        if (slot < 2376) {                       // 4 rows * 66 xp * 9
            int r = slot / 594;
            int rem = slot - r * 594;
            int xp = rem / 9;
            int oct = rem - xp * 9;
            int ys = y0 + r - 1, xs = xp - 1;
            bool valid = (oct < 8) && (ys >= 0) && (ys < 64) && (xs >= 0) && (xs < 64);
            const unsigned short* gp = valid ? (xg + ((ys * 64 + xs) * 256 + cc * 64 + oct * 8))
                                             : zbuf;
            async_cp16(gp, ldsbuf + slot * 8);
        }
    }
}

__global__ __launch_bounds__(256, 2) void c3f_kernel(const __hip_bfloat16* __restrict__ xin,
                                                     const short* __restrict__ wb,
                                                     const float* __restrict__ sc,
                                                     const float* __restrict__ bi,
                                                     const float* __restrict__ zbufF,
                                                     const short* __restrict__ w3b,
                                                     const float* __restrict__ bf3,
                                                     const float* __restrict__ img,
                                                     const float* __restrict__ addw,
                                                     float* __restrict__ outF) {
    __shared__ __attribute__((aligned(16))) short lds[2][19008];   // 2 x 38016 B
    __shared__ float pr2[256];
    __shared__ float invs[64];
    __shared__ float ls_b3[256];
    // bijective XCD swizzle: 512 blocks, 8 XCDs, 64 per XCD contiguous
    int blk0 = blockIdx.x;
    int blk = (blk0 & 7) * 64 + (blk0 >> 3);
    int b = blk >> 5, y0 = (blk & 31) * 2;
    int t = threadIdx.x;
    int w = t >> 6, lane = t & 63;
    int lx = lane & 15, koct = lane >> 4;
    const unsigned short* xg = (const unsigned short*)xin + (size_t)b * 1048576;
    const unsigned short* zbuf = (const unsigned short*)zbufF;
    ls_b3[t] = bf3[t];

    f32x4 acc[8][4];
#pragma unroll
    for (int mi = 0; mi < 8; ++mi)
#pragma unroll
        for (int ni = 0; ni < 4; ++ni) acc[mi][ni] = (f32x4){0.f, 0.f, 0.f, 0.f};

    stage_chunk(xg, lds[0], zbuf, 0, y0, t);
    __syncthreads();

    for (int cc = 0; cc < 4; ++cc) {        // ci chunks of 64
        short* cur = lds[cc & 1];
        if (cc < 3) stage_chunk(xg, lds[(cc + 1) & 1], zbuf, cc + 1, y0, t);
        for (int kk = 0; kk < 9; ++kk) {
            int ky = kk / 3, kx = kk - ky * 3;
#pragma unroll
            for (int k32 = 0; k32 < 2; ++k32) {
                const short* wp = wb + ((((kk * 8 + cc * 2 + k32) * 16) + w * 4) * 64 + lane) * 8;
                bf16x8 bfr[4];
#pragma unroll
                for (int ni = 0; ni < 4; ++ni)
                    bfr[ni] = *(const bf16x8*)(wp + ni * 512);
                bf16x8 afr[8];
#pragma unroll
                for (int mi = 0; mi < 8; ++mi) {
                    int row = mi >> 2, xb = (mi & 3) * 16;
                    afr[mi] = *(const bf16x8*)&cur[((row + ky) * 66 + xb + lx + kx) * 72 + k32 * 32 + koct * 8];
                }
#pragma unroll
                for (int mi = 0; mi < 8; ++mi)
#pragma unroll
                    for (int ni = 0; ni < 4; ++ni)
                        acc[mi][ni] = __builtin_amdgcn_mfma_f32_16x16x32_bf16(afr[mi], bfr[ni], acc[mi][ni], 0, 0, 0);
            }
        }
        __syncthreads();
    }

    // ---- fused final: per row, Wf3 GEMM from LDS restage + v_add + l2norm ----
    float aw = tanhf(addw[0]);
    float ca = 1.f + aw, cb = 1.f - aw;
    short* ep  = &lds[0][0];    // f2 bf16 [x][ci], stride 264
    short* wst = &lds[1][0];    // w  bf16 [co][x], stride 66
#pragma unroll
    for (int r2 = 0; r2 < 2; ++r2) {
        // f2 row: silu(acc*sc+bi) -> ep [x][ci]
#pragma unroll
        for (int mi4 = 0; mi4 < 4; ++mi4) {
            int mi = r2 * 4 + mi4;
#pragma unroll
            for (int ni = 0; ni < 4; ++ni) {
                int co = w * 64 + ni * 16 + lx;
                float s = sc[co], bb2 = bi[co];
#pragma unroll
                for (int rr = 0; rr < 4; ++rr) {
                    int x = mi4 * 16 + koct * 4 + rr;
                    float yv = fmaf(acc[mi][ni][rr], s, bb2);
                    ep[x * 264 + co] = (short)f2bf_(siluf_(yv));
                }
            }
        }
        __syncthreads();
        // GEMM2: Wf3 on this row
        f32x4 acc2[4][4];
#pragma unroll
        for (int mi = 0; mi < 4; ++mi)
#pragma unroll
            for (int ni = 0; ni < 4; ++ni) acc2[mi][ni] = (f32x4){0.f, 0.f, 0.f, 0.f};
#pragma unroll
        for (int k32 = 0; k32 < 8; ++k32) {
            const short* wp = w3b + (((k32 * 16) + w * 4) * 64 + lane) * 8;
            bf16x8 bfr[4];
#pragma unroll
            for (int ni = 0; ni < 4; ++ni) bfr[ni] = *(const bf16x8*)(wp + ni * 512);
            bf16x8 afr[4];
#pragma unroll
            for (int mi = 0; mi < 4; ++mi)
                afr[mi] = *(const bf16x8*)&ep[(mi * 16 + lx) * 264 + k32 * 32 + koct * 8];
#pragma unroll
            for (int mi = 0; mi < 4; ++mi)
#pragma unroll
                for (int ni = 0; ni < 4; ++ni)
                    acc2[mi][ni] = __builtin_amdgcn_mfma_f32_16x16x32_bf16(afr[mi], bfr[ni], acc2[mi][ni], 0, 0, 0);
        }
        // w = acc2 + bf3 -> wst bf16 [co][x] (v_film << img; bf16 ok)
#pragma unroll
        for (int mi = 0; mi < 4; ++mi)
#pragma unroll
            for (int ni = 0; ni < 4; ++ni) {
                int co = w * 64 + ni * 16 + lx;
                float b3 = ls_b3[co];
#pragma unroll
                for (int rr = 0; rr < 4; ++rr) {
                    int x = mi * 16 + koct * 4 + rr;
                    wst[co * 66 + x] = (short)f2bf_(acc2[mi][ni][rr] + b3);
                }
            }
        __syncthreads();
        // coalesced two-pass: v = ca*img + cb*w ; l2norm over co ; store fp32 NCHW
        int x = t & 63, cg = t >> 6;
        const float* ip = img + (size_t)b * 1048576 + (size_t)(y0 + r2) * 64 + x;
        float ss = 0.f;
#pragma unroll 8
        for (int j = 0; j < 64; ++j) {
            int co = cg * 64 + j;
            float v = fmaf(cb, bf2f_((unsigned short)wst[co * 66 + x]), ca * ip[(size_t)co * 4096]);
            ss += v * v;
        }
        pr2[cg * 64 + x] = ss;
        __syncthreads();
        if (t < 64)
            invs[t] = 1.f / fmaxf(sqrtf(pr2[t] + pr2[64 + t] + pr2[128 + t] + pr2[192 + t]), 1e-12f);
        __syncthreads();
        float iv = invs[x];
        float* op = outF + (size_t)b * 1048576 + (size_t)(y0 + r2) * 64 + x;
#pragma unroll 8
        for (int j = 0; j < 64; ++j) {
            int co = cg * 64 + j;
            float v = fmaf(cb, bf2f_((unsigned short)wst[co * 66 + x]), ca * ip[(size_t)co * 4096]);
            op[(size_t)co * 4096] = v * iv;
        }
        __syncthreads();
    }
}

// ---------------- launch ----------------
extern "C" void kernel_launch(void* const* d_in, const int* in_sizes, int n_in,
                              void* d_out, int out_size, void* d_ws, size_t ws_size,
                              hipStream_t stream) {
    const float* img     = (const float*)d_in[0];
    const float* flang   = (const float*)d_in[1];
    const int*   wmask   = (const int*)d_in[2];
    const float* sigma_w = (const float*)d_in[3];
    const float* W1      = (const float*)d_in[4];
    const float* b1      = (const float*)d_in[5];
    const float* W2      = (const float*)d_in[6];
    const float* b2      = (const float*)d_in[7];
    const float* Wv      = (const float*)d_in[8];
    const float* sv      = (const float*)d_in[9];
    const float* bv      = (const float*)d_in[10];
    const float* Wg      = (const float*)d_in[11];
    const float* sg      = (const float*)d_in[12];
    const float* bg      = (const float*)d_in[13];
    const float* Wb      = (const float*)d_in[14];
    const float* sb      = (const float*)d_in[15];
    const float* bb      = (const float*)d_in[16];
    const float* Wf1     = (const float*)d_in[17];
    const float* sf1     = (const float*)d_in[18];
    const float* bf1     = (const float*)d_in[19];
    const float* Wf2     = (const float*)d_in[20];
    const float* sf2     = (const float*)d_in[21];
    const float* bf2     = (const float*)d_in[22];
    const float* Wf3     = (const float*)d_in[23];
    const float* bf3     = (const float*)d_in[24];
    const float* Ws      = (const float*)d_in[25];
    const float* bs      = (const float*)d_in[26];
    const float* addw    = (const float*)d_in[27];
    float* out = (float*)d_out;
    float* ws  = (float*)d_ws;

    // workspace layout (float offsets)
    short* WvB  = (short*)ws;                     // 32768 f
    short* W1B  = (short*)(ws + 32768);           // 32768 f
    short* W3B  = (short*)(ws + 65536);           // 32768 f
    short* WB2  = (short*)(ws + 98304);           // 294912 f -> ends 393216
    float* ycxc = ws + 393216;                    // 256
    float* po   = ws + 393472;                    // 32768 used (region 36864) -> ends 430336
    float* zbuf = ws + 430336;                    // 16 (zeros, written by mega1 prep)
    __hip_bfloat16* bufB = (__hip_bfloat16*)(ws + 430352);   // 16.78M bf16 NHWC

    // 1) langmlp (first, overlaps) + wsum (wave/plane, fused Ws-dot -> po) + prep
    mega1_kernel<<<M1_GRID, 256, 0, stream>>>(Wv, Wf1, Wf3, Wf2, WvB, W1B, W3B, WB2, zbuf,
                                              img, po, Ws, flang, wmask, W1, b1, W2, b2, ycxc);
    // 2) f1 = silu(Wf1 * l2norm(g*tanh(silu(Wv*img*sv+bv)) + bmax) * sf1 + bf1)  (sigw from po)
    f01_kernel<<<1024, 256, 0, stream>>>(img, WvB, W1B, sv, bv, sf1, bf1,
                                         po, bs, ycxc, sigma_w,
                                         Wg, sg, bg, Wb, sb, bb, bufB);
    // 3) f2 = silu(Wf2(3x3)*f1) ; out = l2norm((1+aw)*img + (1-aw)*(Wf3*f2 + bf3))
    c3f_kernel<<<512, 256, 0, stream>>>(bufB, WB2, sf2, bf2, zbuf, W3B, bf3, img, addw, out);
}